// Round 1
// baseline (450.767 us; speedup 1.0000x reference)
//
#include <hip/hip_runtime.h>

// Cost-volume / correlation layer, fp32.
// out[b, dy*9+dx, h, w] = (1/C) * sum_c first[b,c,h,w] * second[b,c,h+dy-4,w+dx-4]
// (zero outside bounds).  B=8, C=128, H=W=128, search_range=4 -> 81 offsets.
//
// Round-4: R3 was latency-bound (VALUBusy 29%, HBM 12.8%, occupancy 44%
// grid-capped: 4608 waves vs 8192 slots).  This round:
//  - 512-thread blocks: two 256-thread halves each reduce half of C
//    (c in [0,64) / [64,128)), combined through a 36 KiB LDS buffer.
//    Same 1152 blocks but 8 waves each -> 9216 waves -> ~90% occupancy,
//    8 waves/SIMD (VGPR<=64 via launch_bounds; 4 blocks/CU * 36KiB LDS ok).
//  - pointer-bump addressing in the pipeline (no 64-bit mul + clamp per
//    prefetch; tail peeled so no clamp is ever needed).

constexpr int B = 8, C = 128, H = 128, W = 128;
constexpr int RNG = 4, MO = 9;   // search range, max_offset = 2*RNG+1
constexpr int RW  = 4;           // pixels per thread along w
constexpr int TY  = 8;           // pixel rows per block
constexpr int C2  = C / 2;       // channels per half-block
constexpr int HWc = H * W;       // 16384, fits int

__global__ __launch_bounds__(512, 8) void corr_kernel(
    const float* __restrict__ first,
    const float* __restrict__ second,
    float* __restrict__ out)
{
    const int tx    = threadIdx.x;        // 0..31
    const int ty    = threadIdx.y;        // 0..15
    const int row   = ty & 7;             // pixel row within block
    const int chalf = ty >> 3;            // 0: c in [0,64)   1: c in [64,128)
    const int h  = blockIdx.x * TY + row; // 0..127
    const int dy = blockIdx.y;            // 0..8
    const int b  = blockIdx.z;
    const int w0 = tx * RW;               // 0..124

    __shared__ __align__(16) float red[TY][MO][32][RW];   // 36 KiB

    float acc[MO][RW];
#pragma unroll
    for (int dx = 0; dx < MO; ++dx)
#pragma unroll
        for (int p = 0; p < RW; ++p) acc[dx][p] = 0.0f;

    const int  srow_i = h + dy - RNG;
    const bool rvalid = (srow_i >= 0) && (srow_i < H);
    const int  srow_c = srow_i < 0 ? 0 : (srow_i >= H ? H - 1 : srow_i);

    // Column edges: tx==0 needs cols -4..-1 (zero), tx==31 needs 128..131.
    const bool ledge = (tx == 0);
    const bool redge = (tx == 31);
    const int off0 = ledge ? 0       : (w0 - 4);   // all 16B-aligned
    const int off2 = redge ? (W - 8) : (w0 + 4);

    if (rvalid) {
        const int cbase = (b * C + chalf * C2) * HWc;
        const float* fp  = first  + cbase + h * W + w0;
        const float* s0p = second + cbase + srow_c * W + off0;
        const float* s1p = second + cbase + srow_c * W + w0;
        const float* s2p = second + cbase + srow_c * W + off2;

        // ---- software pipeline: prefetch distance 1, ping-pong regs ----
        float4 fA, a0A, a1A, a2A, fB, a0B, a1B, a2B;

        // prologue: load c = 0 (of this half) into set A
        fA  = *(const float4*)(fp);
        a0A = *(const float4*)(s0p);
        a1A = *(const float4*)(s1p);
        a2A = *(const float4*)(s2p);

#define PREFETCH(SET)                                                       \
        {                                                                   \
            fp += HWc; s0p += HWc; s1p += HWc; s2p += HWc;                  \
            f##SET  = *(const float4*)(fp);                                 \
            a0##SET = *(const float4*)(s0p);                                \
            a1##SET = *(const float4*)(s1p);                                \
            a2##SET = *(const float4*)(s2p);                                \
        }

#define COMPUTE(SET)                                                        \
        {                                                                   \
            float4 z0 = a0##SET, z2 = a2##SET;                              \
            if (ledge) z0 = make_float4(0.f, 0.f, 0.f, 0.f);                \
            if (redge) z2 = make_float4(0.f, 0.f, 0.f, 0.f);                \
            float fv[RW] = {f##SET.x, f##SET.y, f##SET.z, f##SET.w};        \
            float s[12]  = {z0.x, z0.y, z0.z, z0.w,                         \
                            a1##SET.x, a1##SET.y, a1##SET.z, a1##SET.w,     \
                            z2.x, z2.y, z2.z, z2.w};                        \
            _Pragma("unroll")                                               \
            for (int dx = 0; dx < MO; ++dx)                                 \
                _Pragma("unroll")                                           \
                for (int p = 0; p < RW; ++p)                                \
                    acc[dx][p] += fv[p] * s[p + dx];                        \
        }

        for (int i = 0; i < C2 / 2 - 1; ++i) {   // 31 iterations, c = 2i..2i+1
            PREFETCH(B)   // loads for c+1
            COMPUTE(A)    // FMAs for c   (overlap B's loads)
            PREFETCH(A)   // loads for c+2
            COMPUTE(B)    // FMAs for c+1 (overlap A's loads)
        }
        // tail: A holds c = C2-2; fetch c = C2-1, no further prefetch.
        PREFETCH(B)
        COMPUTE(A)
        COMPUTE(B)
#undef PREFETCH
#undef COMPUTE
    }

    // ---- combine the two C-halves through LDS ----
    if (chalf) {
#pragma unroll
        for (int dx = 0; dx < MO; ++dx)
            *(float4*)&red[row][dx][tx][0] =
                make_float4(acc[dx][0], acc[dx][1], acc[dx][2], acc[dx][3]);
    }
    __syncthreads();
    if (!chalf) {
        const float inv = 1.0f / (float)C;
        const size_t HW = (size_t)H * W;
        float* obase = out + ((size_t)b * (MO * MO) + (size_t)dy * MO) * HW
                           + (size_t)h * W + w0;
#pragma unroll
        for (int dx = 0; dx < MO; ++dx) {
            float4 r = *(const float4*)&red[row][dx][tx][0];
            float4 v = make_float4((acc[dx][0] + r.x) * inv,
                                   (acc[dx][1] + r.y) * inv,
                                   (acc[dx][2] + r.z) * inv,
                                   (acc[dx][3] + r.w) * inv);
            *(float4*)(obase + (size_t)dx * HW) = v;
        }
    }
}

extern "C" void kernel_launch(void* const* d_in, const int* in_sizes, int n_in,
                              void* d_out, int out_size, void* d_ws, size_t ws_size,
                              hipStream_t stream) {
    const float* first  = (const float*)d_in[0];
    const float* second = (const float*)d_in[1];
    float* out = (float*)d_out;

    dim3 grid(H / TY, MO, B);   // (16, 9, 8) = 1152 blocks
    dim3 block(32, 2 * TY);     // 512 threads = 8 waves
    corr_kernel<<<grid, block, 0, stream>>>(first, second, out);
}

// Round 2
// 237.508 us; speedup vs baseline: 1.8979x; 1.8979x over previous
//
#include <hip/hip_runtime.h>

// Cost-volume / correlation layer, fp32.
// out[b, dy*9+dx, h, w] = (1/C) * sum_c first[b,c,h,w] * second[b,c,h+dy-4,w+dx-4]
// (zero outside bounds).  B=8, C=128, H=W=128, search_range=4 -> 81 offsets.
//
// Round-5: R4 (512-thr split-C, launch_bounds(512,8)) spilled: VGPR forced to
// 32, acc[36] went to scratch (WRITE_SIZE 41->410 MB), 2.5x slower.  Post-
// mortem insight: R3's VGPR=44 proves its ping-pong pipeline was ALSO defeated
// by regalloc (needs ~70 regs); only ~1-2 loads in flight per wave at 4.5
// waves/SIMD -> latency-bound (VALUBusy 29%).
// This round: 256-thr structure, __launch_bounds__(256,4) -> 128-VGPR budget
// (grid caps occupancy at ~4.5 waves/SIMD anyway, so extra regs are free).
// True prefetch-distance-2: 3 rotating register sets = 8 loads in flight per
// wave.  Pointer-bump addressing (no per-c 64-bit mul), peeled prologue/tail.

constexpr int B = 8, C = 128, H = 128, W = 128;
constexpr int RNG = 4, MO = 9;   // search range, max_offset = 2*RNG+1
constexpr int RW  = 4;           // pixels per thread along w
constexpr int TY  = 8;           // pixel rows per block
constexpr int HWc = H * W;       // 16384, fits int

__global__ __launch_bounds__(256, 4) void corr_kernel(
    const float* __restrict__ first,
    const float* __restrict__ second,
    float* __restrict__ out)
{
    const int tx = threadIdx.x;           // 0..31
    const int ty = threadIdx.y;           // 0..7
    const int h  = blockIdx.x * TY + ty;  // 0..127
    const int dy = blockIdx.y;            // 0..8
    const int b  = blockIdx.z;
    const int w0 = tx * RW;               // 0..124

    float acc[MO][RW];
#pragma unroll
    for (int dx = 0; dx < MO; ++dx)
#pragma unroll
        for (int p = 0; p < RW; ++p) acc[dx][p] = 0.0f;

    const int  srow_i = h + dy - RNG;
    const bool rvalid = (srow_i >= 0) && (srow_i < H);
    const int  srow_c = srow_i < 0 ? 0 : (srow_i >= H ? H - 1 : srow_i);

    // Column edges: tx==0 needs cols -4..-1 (zero), tx==31 needs 128..131.
    const bool ledge = (tx == 0);
    const bool redge = (tx == 31);
    const int off0 = ledge ? 0       : (w0 - 4);   // all 16B-aligned
    const int off2 = redge ? (W - 8) : (w0 + 4);

    if (rvalid) {
        const int cbase = b * C * HWc;
        const float* fp  = first  + cbase + h * W + w0;
        const float* s0p = second + cbase + srow_c * W + off0;
        const float* s1p = second + cbase + srow_c * W + w0;
        const float* s2p = second + cbase + srow_c * W + off2;

        // ---- software pipeline: prefetch distance 2, 3 rotating sets ----
        float4 fA, a0A, a1A, a2A;
        float4 fB, a0B, a1B, a2B;
        float4 fC, a0C, a1C, a2C;

#define LOAD(SET)                                                           \
        {                                                                   \
            f##SET  = *(const float4*)(fp);                                 \
            a0##SET = *(const float4*)(s0p);                                \
            a1##SET = *(const float4*)(s1p);                                \
            a2##SET = *(const float4*)(s2p);                                \
            fp += HWc; s0p += HWc; s1p += HWc; s2p += HWc;                  \
        }

#define COMPUTE(SET)                                                        \
        {                                                                   \
            float4 z0 = a0##SET, z2 = a2##SET;                              \
            if (ledge) z0 = make_float4(0.f, 0.f, 0.f, 0.f);                \
            if (redge) z2 = make_float4(0.f, 0.f, 0.f, 0.f);                \
            float fv[RW] = {f##SET.x, f##SET.y, f##SET.z, f##SET.w};        \
            float s[12]  = {z0.x, z0.y, z0.z, z0.w,                         \
                            a1##SET.x, a1##SET.y, a1##SET.z, a1##SET.w,     \
                            z2.x, z2.y, z2.z, z2.w};                        \
            _Pragma("unroll")                                               \
            for (int dx = 0; dx < MO; ++dx)                                 \
                _Pragma("unroll")                                           \
                for (int p = 0; p < RW; ++p)                                \
                    acc[dx][p] += fv[p] * s[p + dx];                        \
        }

        LOAD(A)   // c = 0
        LOAD(B)   // c = 1
        for (int i = 0; i < (C - 2) / 3; ++i) {   // 42 iters: c = 3i..3i+2
            LOAD(C)      // c = 3i+2   (consumed 2 COMPUTEs later)
            COMPUTE(A)   // c = 3i
            LOAD(A)      // c = 3i+3
            COMPUTE(B)   // c = 3i+1
            LOAD(B)      // c = 3i+4
            COMPUTE(C)   // c = 3i+2
        }
        // after loop: A holds c=126, B holds c=127; exactly 128 loads issued.
        COMPUTE(A)
        COMPUTE(B)
#undef LOAD
#undef COMPUTE
    }

    const float inv = 1.0f / (float)C;
    const size_t HW = (size_t)H * W;
    float* obase = out + ((size_t)b * (MO * MO) + (size_t)dy * MO) * HW
                       + (size_t)h * W + w0;
#pragma unroll
    for (int dx = 0; dx < MO; ++dx) {
        float4 v = make_float4(acc[dx][0] * inv, acc[dx][1] * inv,
                               acc[dx][2] * inv, acc[dx][3] * inv);
        *(float4*)(obase + (size_t)dx * HW) = v;
    }
}

extern "C" void kernel_launch(void* const* d_in, const int* in_sizes, int n_in,
                              void* d_out, int out_size, void* d_ws, size_t ws_size,
                              hipStream_t stream) {
    const float* first  = (const float*)d_in[0];
    const float* second = (const float*)d_in[1];
    float* out = (float*)d_out;

    dim3 grid(H / TY, MO, B);   // (16, 9, 8) = 1152 blocks
    dim3 block(32, TY);         // 256 threads
    corr_kernel<<<grid, block, 0, stream>>>(first, second, out);
}